// Round 2
// baseline (389.462 us; speedup 1.0000x reference)
//
#include <hip/hip_runtime.h>
#include <math.h>

typedef unsigned short u16;
typedef unsigned int   u32;

#define NB     32768   // batch rows
#define ND     512     // d_in
#define NM     2048    // memory slots
#define TAUINV 10.0f
#define FBETA  10.0f
#define FTHETA 0.5f
#define FGAMMA 0.5f
#define CMAX   32      // candidate cap per row
#define MARGIN 2e-3f   // >> any realistic bf16-GEMM error

typedef __bf16 bf16x8 __attribute__((ext_vector_type(8)));
typedef float  f32x4  __attribute__((ext_vector_type(4)));

__device__ __forceinline__ u16 f2bf(float x) {
    u32 b = __float_as_uint(x);
    u32 r = (b + 0x7FFFu + ((b >> 16) & 1u)) >> 16;   // RNE
    return (u16)r;
}

// ---------------- row L2-normalize (f32 in -> bf16 bits out) ----------------
__global__ __launch_bounds__(256) void rownorm_kernel(const float* __restrict__ in,
                                                      u16* __restrict__ out, int nrows) {
    int row  = blockIdx.x * 4 + (threadIdx.x >> 6);
    if (row >= nrows) return;
    int lane = threadIdx.x & 63;
    const float4* p = (const float4*)(in + (size_t)row * ND);
    float4 a = p[lane * 2], b = p[lane * 2 + 1];
    float ss = a.x*a.x + a.y*a.y + a.z*a.z + a.w*a.w +
               b.x*b.x + b.y*b.y + b.z*b.z + b.w*b.w;
    #pragma unroll
    for (int off = 1; off < 64; off <<= 1) ss += __shfl_xor(ss, off, 64);
    float sc = 1.0f / fmaxf(sqrtf(ss), 1e-12f);
    uint4 o;
    o.x = (u32)f2bf(a.x*sc) | ((u32)f2bf(a.y*sc) << 16);
    o.y = (u32)f2bf(a.z*sc) | ((u32)f2bf(a.w*sc) << 16);
    o.z = (u32)f2bf(b.x*sc) | ((u32)f2bf(b.y*sc) << 16);
    o.w = (u32)f2bf(b.z*sc) | ((u32)f2bf(b.w*sc) << 16);
    ((uint4*)(out + (size_t)row * ND))[lane] = o;
}

// ---------------- per-slot fp64 inverse norms of K ----------------
__global__ __launch_bounds__(256) void knorm_kernel(const float* __restrict__ K,
                                                    double* __restrict__ invKn) {
    int row  = blockIdx.x * 4 + (threadIdx.x >> 6);
    int lane = threadIdx.x & 63;
    const float4* p = (const float4*)(K + (size_t)row * ND);
    float4 a = p[lane * 2], b = p[lane * 2 + 1];
    double ss = (double)a.x*a.x + (double)a.y*a.y + (double)a.z*a.z + (double)a.w*a.w +
                (double)b.x*b.x + (double)b.y*b.y + (double)b.z*b.z + (double)b.w*b.w;
    #pragma unroll
    for (int off = 1; off < 64; off <<= 1) ss += __shfl_xor(ss, off, 64);
    if (lane == 0) invKn[row] = 1.0 / fmax(sqrt(ss), 1e-12);
}

// ---------------- logs = log(s+eps); counts = 0 ----------------
__global__ void prep_kernel(const float* __restrict__ s, float* __restrict__ logs,
                            float* __restrict__ counts) {
    int i = blockIdx.x * 256 + threadIdx.x;
    if (i < NM) { logs[i] = logf(s[i] + 1e-8f); counts[i] = 0.0f; }
}

// ---------------- GEMM: S[r][c] = sum_k Xn[r][k]*Kn[c][k], packed idx ----------------
#define BKT 64
__global__ __launch_bounds__(256) void gemm_kernel(const u16* __restrict__ Xn,
                                                   const u16* __restrict__ Kn,
                                                   float* __restrict__ S) {
    __shared__ u16 As[2][128 * BKT];   // 16 KB each
    __shared__ u16 Bs[2][128 * BKT];
    const int tid  = threadIdx.x;
    const int lane = tid & 63;
    const int wid  = tid >> 6;
    const int wr = wid >> 1, wc = wid & 1;
    const int rowA = blockIdx.y * 128;
    const int colB = blockIdx.x * 128;

    f32x4 acc[4][4];
    #pragma unroll
    for (int m = 0; m < 4; m++)
        #pragma unroll
        for (int n = 0; n < 4; n++) acc[m][n] = (f32x4){0.f, 0.f, 0.f, 0.f};

    auto stage = [&](int buf, int kt) {
        #pragma unroll
        for (int i = 0; i < 4; i++) {
            int lo = (i * 256 + tid) * 16;   // byte offset in 16KB tile
            int r  = lo >> 7;                // 128 B per LDS row
            int cb = lo & 127;
            const char* ga = (const char*)(Xn + (size_t)(rowA + r) * ND + kt * BKT) + cb;
            __builtin_amdgcn_global_load_lds((const __attribute__((address_space(1))) void*)ga,
                (__attribute__((address_space(3))) void*)((char*)(&As[buf][0]) + lo), 16, 0, 0);
            const char* gb = (const char*)(Kn + (size_t)(colB + r) * ND + kt * BKT) + cb;
            __builtin_amdgcn_global_load_lds((const __attribute__((address_space(1))) void*)gb,
                (__attribute__((address_space(3))) void*)((char*)(&Bs[buf][0]) + lo), 16, 0, 0);
        }
    };

    stage(0, 0);
    __syncthreads();
    int cur = 0;
    for (int kt = 0; kt < ND / BKT; ++kt) {
        if (kt + 1 < ND / BKT) stage(cur ^ 1, kt + 1);
        #pragma unroll
        for (int ks = 0; ks < 2; ++ks) {
            const int kof = ks * 32 + (lane >> 4) * 8;
            bf16x8 af[4], bq[4];
            #pragma unroll
            for (int m = 0; m < 4; m++) {
                int r = wr * 64 + m * 16 + (lane & 15);
                af[m] = *(const bf16x8*)(&As[cur][r * BKT + kof]);
            }
            #pragma unroll
            for (int n = 0; n < 4; n++) {
                int c = wc * 64 + n * 16 + (lane & 15);
                bq[n] = *(const bf16x8*)(&Bs[cur][c * BKT + kof]);
            }
            #pragma unroll
            for (int m = 0; m < 4; m++)
                #pragma unroll
                for (int n = 0; n < 4; n++)
                    acc[m][n] = __builtin_amdgcn_mfma_f32_16x16x32_bf16(af[m], bq[n], acc[m][n], 0, 0, 0);
        }
        __syncthreads();
        cur ^= 1;
    }

    // epilogue: pack global col into low 11 mantissa bits, store fp32
    #pragma unroll
    for (int m = 0; m < 4; m++) {
        int r0 = rowA + wr * 64 + m * 16 + ((lane >> 4) * 4);
        #pragma unroll
        for (int n = 0; n < 4; n++) {
            int c = colB + wc * 64 + n * 16 + (lane & 15);
            #pragma unroll
            for (int j = 0; j < 4; j++) {
                u32 bits = (__float_as_uint(acc[m][n][j]) & 0xFFFFF800u) | (u32)c;
                S[(size_t)(r0 + j) * NM + c] = __uint_as_float(bits);
            }
        }
    }
}

// ---------------- per-row candidate selection (approx top-8 + margin) ----------------
#define INS(VV) { float x_ = (VV); float h_;                      \
    h_ = fmaxf(t0, x_); x_ = fminf(t0, x_); t0 = h_;              \
    h_ = fmaxf(t1, x_); x_ = fminf(t1, x_); t1 = h_;              \
    h_ = fmaxf(t2, x_); x_ = fminf(t2, x_); t2 = h_;              \
    h_ = fmaxf(t3, x_); x_ = fminf(t3, x_); t3 = h_;              \
    h_ = fmaxf(t4, x_); x_ = fminf(t4, x_); t4 = h_;              \
    h_ = fmaxf(t5, x_); x_ = fminf(t5, x_); t5 = h_;              \
    h_ = fmaxf(t6, x_); x_ = fminf(t6, x_); t6 = h_;              \
    h_ = fmaxf(t7, x_); x_ = fminf(t7, x_); t7 = h_; }

#define ROUND(G) {                                                \
    float mv = t0;                                                \
    mv = fmaxf(mv, __shfl_xor(mv, 1, 64));                        \
    mv = fmaxf(mv, __shfl_xor(mv, 2, 64));                        \
    mv = fmaxf(mv, __shfl_xor(mv, 4, 64));                        \
    mv = fmaxf(mv, __shfl_xor(mv, 8, 64));                        \
    mv = fmaxf(mv, __shfl_xor(mv, 16, 64));                       \
    mv = fmaxf(mv, __shfl_xor(mv, 32, 64));                       \
    G = mv;                                                       \
    bool pop = (t0 == mv);                                        \
    t0 = pop ? t1 : t0; t1 = pop ? t2 : t1; t2 = pop ? t3 : t2;   \
    t3 = pop ? t4 : t3; t4 = pop ? t5 : t4; t5 = pop ? t6 : t5;   \
    t6 = pop ? t7 : t6; t7 = pop ? -__builtin_inff() : t7; }

__global__ __launch_bounds__(256) void cand_kernel(const float* __restrict__ S,
        u16* __restrict__ cand, int* __restrict__ ccnt, int rowBase) {
    __shared__ int scnt[4];
    int w    = threadIdx.x >> 6;
    int lane = threadIdx.x & 63;
    int lrow = blockIdx.x * 4 + w;
    if (lane == 0) scnt[w] = 0;
    __syncthreads();

    const float4* p = (const float4*)(S + (size_t)lrow * NM);
    float4 v[8];
    float t0 = -__builtin_inff(), t1 = t0, t2 = t0, t3 = t0, t4 = t0, t5 = t0, t6 = t0, t7 = t0;
    #pragma unroll
    for (int it = 0; it < 8; ++it) {
        v[it] = p[it * 64 + lane];
        INS(v[it].x); INS(v[it].y); INS(v[it].z); INS(v[it].w);
    }
    float g0, g1, g2, g3, g4, g5, g6, g7;
    ROUND(g0); ROUND(g1); ROUND(g2); ROUND(g3);
    ROUND(g4); ROUND(g5); ROUND(g6); ROUND(g7);
    (void)g0; (void)g1; (void)g2; (void)g3; (void)g4; (void)g5; (void)g6;
    float T = __uint_as_float(__float_as_uint(g7) & 0xFFFFF800u) - MARGIN;

    int grow = rowBase + lrow;
    #pragma unroll
    for (int it = 0; it < 8; ++it) {
        float c4[4] = {v[it].x, v[it].y, v[it].z, v[it].w};
        #pragma unroll
        for (int q = 0; q < 4; ++q) {
            if (c4[q] >= T) {
                int pos = atomicAdd(&scnt[w], 1);
                if (pos < CMAX)
                    cand[(size_t)grow * CMAX + pos] = (u16)(__float_as_uint(c4[q]) & 0x7FFu);
            }
        }
    }
    __syncthreads();
    if (lane == 0) ccnt[grow] = min(scnt[w], CMAX);
}

// ---------------- fp64 refine: exact top-8, f, g, winner counts ----------------
__global__ __launch_bounds__(256) void refine_kernel(const float* __restrict__ x,
        const float* __restrict__ K, const double* __restrict__ invKn,
        const u16* __restrict__ cand, const int* __restrict__ ccnt,
        float* __restrict__ top8v, u16* __restrict__ top8i,
        float* __restrict__ f_out, float* __restrict__ g_out, float* __restrict__ counts) {
    int row  = blockIdx.x * 4 + (threadIdx.x >> 6);
    int lane = threadIdx.x & 63;

    const float4* xr = (const float4*)(x + (size_t)row * ND);
    float4 a = xr[lane * 2], b = xr[lane * 2 + 1];
    double x0 = a.x, x1 = a.y, x2 = a.z, x3 = a.w;
    double x4 = b.x, x5 = b.y, x6 = b.z, x7 = b.w;

    double ss = x0*x0 + x1*x1 + x2*x2 + x3*x3 + x4*x4 + x5*x5 + x6*x6 + x7*x7;
    #pragma unroll
    for (int off = 1; off < 64; off <<= 1) ss += __shfl_xor(ss, off, 64);
    double xinv = 1.0 / fmax(sqrt(ss), 1e-12);

    int cnt = ccnt[row];
    int myidx = (lane < cnt) ? (int)cand[(size_t)row * CMAX + lane] : 0;
    double myval = -1e300;

    for (int c = 0; c < cnt; ++c) {
        int ci = __shfl(myidx, c, 64);
        const float4* kr = (const float4*)(K + (size_t)ci * ND);
        float4 k0 = kr[lane * 2], k1 = kr[lane * 2 + 1];
        double acc;
        acc = x0 * (double)k0.x;
        acc = fma(x1, (double)k0.y, acc);
        acc = fma(x2, (double)k0.z, acc);
        acc = fma(x3, (double)k0.w, acc);
        acc = fma(x4, (double)k1.x, acc);
        acc = fma(x5, (double)k1.y, acc);
        acc = fma(x6, (double)k1.z, acc);
        acc = fma(x7, (double)k1.w, acc);
        #pragma unroll
        for (int off = 1; off < 64; off <<= 1) acc += __shfl_xor(acc, off, 64);
        double val = acc * xinv * invKn[ci];
        if (lane == c) myval = val;
    }

    float vals[8]; int idxs[8];
    #pragma unroll
    for (int r = 0; r < 8; ++r) {
        double m = myval;
        #pragma unroll
        for (int off = 1; off < 64; off <<= 1) m = fmax(m, __shfl_xor(m, off, 64));
        unsigned long long bal = __ballot(myval == m);
        int wl = __ffsll(bal) - 1;
        int wi = __shfl(myidx, wl, 64);
        vals[r] = (float)m;
        idxs[r] = wi;
        if (lane == wl) myval = -1e300;
    }

    if (lane == 0) {
        float fv = vals[0];
        f_out[row] = fv;
        g_out[row] = 1.0f / (1.0f + expf(FBETA * (fv - FTHETA)));
        atomicAdd(&counts[idxs[0]], 1.0f);
        float4* tv = (float4*)(top8v + (size_t)row * 8);
        tv[0] = (float4){vals[0], vals[1], vals[2], vals[3]};
        tv[1] = (float4){vals[4], vals[5], vals[6], vals[7]};
        uint4 ip;
        ip.x = (u32)idxs[0] | ((u32)idxs[1] << 16);
        ip.y = (u32)idxs[2] | ((u32)idxs[3] << 16);
        ip.z = (u32)idxs[4] | ((u32)idxs[5] << 16);
        ip.w = (u32)idxs[6] | ((u32)idxs[7] << 16);
        *(uint4*)(top8i + (size_t)row * 8) = ip;
    }
}

// ---------------- finalize: softmax(8), attn row (zeros+scatter), y = g * attn@V ----------------
__global__ __launch_bounds__(256) void finalize_kernel(const float* __restrict__ top8v,
        const u16* __restrict__ top8i, const float* __restrict__ counts,
        const float* __restrict__ logs, const float* __restrict__ V,
        const float* __restrict__ g_out, float* __restrict__ y, float* __restrict__ attn) {
    int row  = blockIdx.x * 4 + (threadIdx.x >> 6);
    int lane = threadIdx.x & 63;
    // zero the attn row (replaces a separate 268 MB memset pass)
    float4 z = {0.f, 0.f, 0.f, 0.f};
    float4* arow = (float4*)(attn + (size_t)row * NM);
    #pragma unroll
    for (int i = 0; i < 8; i++) arow[i * 64 + lane] = z;

    float logit = -__builtin_inff();
    int idx = 0;
    if (lane < 8) {
        idx = (int)top8i[(size_t)row * 8 + lane];
        float val = top8v[(size_t)row * 8 + lane];
        logit = val * TAUINV + logs[idx] - (FGAMMA / (float)NB) * counts[idx];
    }
    float mv = logit;
    mv = fmaxf(mv, __shfl_xor(mv, 1, 64));
    mv = fmaxf(mv, __shfl_xor(mv, 2, 64));
    mv = fmaxf(mv, __shfl_xor(mv, 4, 64));
    float e = (lane < 8) ? expf(logit - mv) : 0.0f;
    float sum = e;
    sum += __shfl_xor(sum, 1, 64);
    sum += __shfl_xor(sum, 2, 64);
    sum += __shfl_xor(sum, 4, 64);
    float w = e / sum;   // garbage on lanes >=8, never consumed

    // order the zero-stores before the scatter (different lanes may hit same address)
    asm volatile("s_waitcnt vmcnt(0)" ::: "memory");
    if (lane < 8) attn[(size_t)row * NM + idx] = w;

    float4 acc0 = z, acc1 = z;
    #pragma unroll
    for (int j = 0; j < 8; j++) {
        float wj = __shfl(w, j, 64);
        int   ij = __shfl(idx, j, 64);
        const float4* vr = (const float4*)(V + (size_t)ij * 512);
        float4 v0 = vr[lane * 2], v1 = vr[lane * 2 + 1];
        acc0.x += wj * v0.x; acc0.y += wj * v0.y; acc0.z += wj * v0.z; acc0.w += wj * v0.w;
        acc1.x += wj * v1.x; acc1.y += wj * v1.y; acc1.z += wj * v1.z; acc1.w += wj * v1.w;
    }
    float gr = g_out[row];
    float4 o0 = {gr * acc0.x, gr * acc0.y, gr * acc0.z, gr * acc0.w};
    float4 o1 = {gr * acc1.x, gr * acc1.y, gr * acc1.z, gr * acc1.w};
    float4* yp = (float4*)(y + (size_t)row * 512);
    yp[lane * 2]     = o0;
    yp[lane * 2 + 1] = o1;
}

extern "C" void kernel_launch(void* const* d_in, const int* in_sizes, int n_in,
                              void* d_out, int out_size, void* d_ws, size_t ws_size,
                              hipStream_t stream) {
    const float* x = (const float*)d_in[0];
    const float* K = (const float*)d_in[1];
    const float* V = (const float*)d_in[2];
    const float* s = (const float*)d_in[3];

    float* y     = (float*)d_out;                       // [32768][512]
    float* f_out = y + (size_t)NB * 512;                // [32768]
    float* g_out = f_out + NB;                          // [32768]
    float* attn  = g_out + NB;                          // [32768][2048]

    char* ws = (char*)d_ws;
    u16*    xn     = (u16*)ws;                          // 33,554,432 B
    u16*    kn     = (u16*)(ws + 33554432);             //  2,097,152 B -> 35,651,584
    float*  logs   = (float*)(ws + 35651584);           //      8,192 B -> 35,659,776
    float*  counts = (float*)(ws + 35659776);           //      8,192 B -> 35,667,968
    double* invKn  = (double*)(ws + 35667968);          //     16,384 B -> 35,684,352
    float*  top8v  = (float*)(ws + 35684352);           //  1,048,576 B -> 36,732,928
    u16*    top8i  = (u16*)(ws + 36732928);             //    524,288 B -> 37,257,216
    int*    ccnt   = (int*)(ws + 37257216);             //    131,072 B -> 37,388,288
    u16*    cand   = (u16*)(ws + 37388288);             //  2,097,152 B -> 39,485,440
    float*  Sbuf   = (float*)(ws + 39485440);           // chunk*2048*4 B

    const size_t sbase = 39485440;
    int chunk = 8192;
    while (chunk > 1024 && sbase + (size_t)chunk * NM * 4 > ws_size) chunk >>= 1;

    rownorm_kernel<<<NB / 4, 256, 0, stream>>>(x, xn, NB);
    rownorm_kernel<<<NM / 4, 256, 0, stream>>>(K, kn, NM);
    knorm_kernel<<<NM / 4, 256, 0, stream>>>(K, invKn);
    prep_kernel<<<NM / 256, 256, 0, stream>>>(s, logs, counts);

    for (int r0 = 0; r0 < NB; r0 += chunk) {
        gemm_kernel<<<dim3(NM / 128, chunk / 128), 256, 0, stream>>>(
            xn + (size_t)r0 * ND, kn, Sbuf);
        cand_kernel<<<chunk / 4, 256, 0, stream>>>(Sbuf, cand, ccnt, r0);
    }
    refine_kernel<<<NB / 4, 256, 0, stream>>>(x, K, invKn, cand, ccnt,
                                              top8v, top8i, f_out, g_out, counts);
    finalize_kernel<<<NB / 4, 256, 0, stream>>>(top8v, top8i, counts, logs, V,
                                                g_out, y, attn);
}

// Round 3
// 359.324 us; speedup vs baseline: 1.0839x; 1.0839x over previous
//
#include <hip/hip_runtime.h>
#include <math.h>

typedef unsigned short u16;
typedef unsigned int   u32;

#define NB     32768   // batch rows
#define ND     512     // d_in
#define NM     2048    // memory slots
#define TAUINV 10.0f
#define FBETA  10.0f
#define FTHETA 0.5f
#define FGAMMA 0.5f
#define CMAX   32      // candidate cap per row
#define MARGIN 3e-3f   // covers bf16-gemm err + bf16-S rounding

typedef __bf16 bf16x8 __attribute__((ext_vector_type(8)));
typedef float  f32x4  __attribute__((ext_vector_type(4)));

__device__ __forceinline__ u16 f2bf(float x) {
    u32 b = __float_as_uint(x);
    u32 r = (b + 0x7FFFu + ((b >> 16) & 1u)) >> 16;   // RNE
    return (u16)r;
}
__device__ __forceinline__ float bf2f(u32 h) { return __uint_as_float(h << 16); }

// ---------------- x rows: L2-normalize (f32 -> bf16) ----------------
__global__ __launch_bounds__(256) void rownorm_kernel(const float* __restrict__ in,
                                                      u16* __restrict__ out) {
    int row  = blockIdx.x * 4 + (threadIdx.x >> 6);
    int lane = threadIdx.x & 63;
    const float4* p = (const float4*)(in + (size_t)row * ND);
    float4 a = p[lane * 2], b = p[lane * 2 + 1];
    float ss = a.x*a.x + a.y*a.y + a.z*a.z + a.w*a.w +
               b.x*b.x + b.y*b.y + b.z*b.z + b.w*b.w;
    #pragma unroll
    for (int off = 1; off < 64; off <<= 1) ss += __shfl_xor(ss, off, 64);
    float sc = 1.0f / fmaxf(sqrtf(ss), 1e-12f);
    uint4 o;
    o.x = (u32)f2bf(a.x*sc) | ((u32)f2bf(a.y*sc) << 16);
    o.y = (u32)f2bf(a.z*sc) | ((u32)f2bf(a.w*sc) << 16);
    o.z = (u32)f2bf(b.x*sc) | ((u32)f2bf(b.y*sc) << 16);
    o.w = (u32)f2bf(b.z*sc) | ((u32)f2bf(b.w*sc) << 16);
    ((uint4*)(out + (size_t)row * ND))[lane] = o;
}

// ---------------- K rows: bf16-normalize + fp64 inv-norm + logs + counts=0 ----------------
__global__ __launch_bounds__(256) void kprep_kernel(const float* __restrict__ K,
        u16* __restrict__ kn, double* __restrict__ invKn,
        const float* __restrict__ s, float* __restrict__ logs, float* __restrict__ counts) {
    int row  = blockIdx.x * 4 + (threadIdx.x >> 6);
    int lane = threadIdx.x & 63;
    const float4* p = (const float4*)(K + (size_t)row * ND);
    float4 a = p[lane * 2], b = p[lane * 2 + 1];
    double ss = (double)a.x*a.x + (double)a.y*a.y + (double)a.z*a.z + (double)a.w*a.w +
                (double)b.x*b.x + (double)b.y*b.y + (double)b.z*b.z + (double)b.w*b.w;
    #pragma unroll
    for (int off = 1; off < 64; off <<= 1) ss += __shfl_xor(ss, off, 64);
    double inv = 1.0 / fmax(sqrt(ss), 1e-12);
    float sc = (float)inv;
    uint4 o;
    o.x = (u32)f2bf(a.x*sc) | ((u32)f2bf(a.y*sc) << 16);
    o.y = (u32)f2bf(a.z*sc) | ((u32)f2bf(a.w*sc) << 16);
    o.z = (u32)f2bf(b.x*sc) | ((u32)f2bf(b.y*sc) << 16);
    o.w = (u32)f2bf(b.z*sc) | ((u32)f2bf(b.w*sc) << 16);
    ((uint4*)(kn + (size_t)row * ND))[lane] = o;
    if (lane == 0) {
        invKn[row]  = inv;
        logs[row]   = logf(s[row] + 1e-8f);
        counts[row] = 0.0f;
    }
}

// ---------------- GEMM: S2[r][c] (bf16) = Xn[r]·Kn[c], LDS-repacked coalesced store ----------------
#define BKT 64
__global__ __launch_bounds__(256) void gemm_kernel(const u16* __restrict__ Xn,
                                                   const u16* __restrict__ Kn,
                                                   u16* __restrict__ S2) {
    __shared__ u16 smem[4][8192];   // [0..1]=A dbuf, [2..3]=B dbuf; reused as repack tile
    const int tid  = threadIdx.x;
    const int lane = tid & 63;
    const int wid  = tid >> 6;
    const int wr = wid >> 1, wc = wid & 1;

    // XCD-bijective swizzle: 4096 blocks % 8 == 0
    int lin = blockIdx.x;
    int swz = (lin & 7) * 512 + (lin >> 3);
    const int rowA = (swz >> 4) * 128;   // 256 row-panels
    const int colB = (swz & 15) * 128;   // 16 col-panels

    f32x4 acc[4][4];
    #pragma unroll
    for (int m = 0; m < 4; m++)
        #pragma unroll
        for (int n = 0; n < 4; n++) acc[m][n] = (f32x4){0.f, 0.f, 0.f, 0.f};

    auto stage = [&](int buf, int kt) {
        #pragma unroll
        for (int i = 0; i < 4; i++) {
            int lo = (i * 256 + tid) * 16;   // byte offset in 16KB tile
            int r  = lo >> 7;                // 128 B per LDS row
            int cb = lo & 127;
            const char* ga = (const char*)(Xn + (size_t)(rowA + r) * ND + kt * BKT) + cb;
            __builtin_amdgcn_global_load_lds((const __attribute__((address_space(1))) void*)ga,
                (__attribute__((address_space(3))) void*)((char*)(&smem[buf][0]) + lo), 16, 0, 0);
            const char* gb = (const char*)(Kn + (size_t)(colB + r) * ND + kt * BKT) + cb;
            __builtin_amdgcn_global_load_lds((const __attribute__((address_space(1))) void*)gb,
                (__attribute__((address_space(3))) void*)((char*)(&smem[2 + buf][0]) + lo), 16, 0, 0);
        }
    };

    stage(0, 0);
    __syncthreads();
    int cur = 0;
    for (int kt = 0; kt < ND / BKT; ++kt) {
        if (kt + 1 < ND / BKT) stage(cur ^ 1, kt + 1);
        #pragma unroll
        for (int ks = 0; ks < 2; ++ks) {
            const int kof = ks * 32 + (lane >> 4) * 8;
            bf16x8 af[4], bq[4];
            #pragma unroll
            for (int m = 0; m < 4; m++) {
                int r = wr * 64 + m * 16 + (lane & 15);
                af[m] = *(const bf16x8*)(&smem[cur][r * BKT + kof]);
            }
            #pragma unroll
            for (int n = 0; n < 4; n++) {
                int c = wc * 64 + n * 16 + (lane & 15);
                bq[n] = *(const bf16x8*)(&smem[2 + cur][c * BKT + kof]);
            }
            #pragma unroll
            for (int m = 0; m < 4; m++)
                #pragma unroll
                for (int n = 0; n < 4; n++)
                    acc[m][n] = __builtin_amdgcn_mfma_f32_16x16x32_bf16(af[m], bq[n], acc[m][n], 0, 0, 0);
        }
        __syncthreads();
        cur ^= 1;
    }

    // epilogue: bf16-convert through LDS (pad 136 u16/row keeps 16B-aligned rows)
    u16* St = (u16*)&smem[0][0];   // 128 x 136 u16 = 34,816 B
    #pragma unroll
    for (int m = 0; m < 4; m++) {
        int rloc = wr * 64 + m * 16 + (lane >> 4) * 4;
        #pragma unroll
        for (int n = 0; n < 4; n++) {
            int cloc = wc * 64 + n * 16 + (lane & 15);
            #pragma unroll
            for (int j = 0; j < 4; j++)
                St[(rloc + j) * 136 + cloc] = f2bf(acc[m][n][j]);
        }
    }
    __syncthreads();
    int c16 = tid & 15;
    #pragma unroll
    for (int i = 0; i < 8; i++) {
        int r = i * 16 + (tid >> 4);
        uint4 val = *(const uint4*)(St + r * 136 + c16 * 8);
        *(uint4*)(S2 + (size_t)(rowA + r) * NM + colB + c16 * 8) = val;
    }
}

// ---------------- per-row candidate selection (bf16 S, approx top-8 + margin) ----------------
#define INS(VV) { float x_ = (VV); float h_;                      \
    h_ = fmaxf(t0, x_); x_ = fminf(t0, x_); t0 = h_;              \
    h_ = fmaxf(t1, x_); x_ = fminf(t1, x_); t1 = h_;              \
    h_ = fmaxf(t2, x_); x_ = fminf(t2, x_); t2 = h_;              \
    h_ = fmaxf(t3, x_); x_ = fminf(t3, x_); t3 = h_;              \
    h_ = fmaxf(t4, x_); x_ = fminf(t4, x_); t4 = h_;              \
    h_ = fmaxf(t5, x_); x_ = fminf(t5, x_); t5 = h_;              \
    h_ = fmaxf(t6, x_); x_ = fminf(t6, x_); t6 = h_;              \
    h_ = fmaxf(t7, x_); x_ = fminf(t7, x_); t7 = h_; }

#define ROUND(G) {                                                \
    float mv = t0;                                                \
    mv = fmaxf(mv, __shfl_xor(mv, 1, 64));                        \
    mv = fmaxf(mv, __shfl_xor(mv, 2, 64));                        \
    mv = fmaxf(mv, __shfl_xor(mv, 4, 64));                        \
    mv = fmaxf(mv, __shfl_xor(mv, 8, 64));                        \
    mv = fmaxf(mv, __shfl_xor(mv, 16, 64));                       \
    mv = fmaxf(mv, __shfl_xor(mv, 32, 64));                       \
    G = mv;                                                       \
    bool pop = (t0 == mv);                                        \
    t0 = pop ? t1 : t0; t1 = pop ? t2 : t1; t2 = pop ? t3 : t2;   \
    t3 = pop ? t4 : t3; t4 = pop ? t5 : t4; t5 = pop ? t6 : t5;   \
    t6 = pop ? t7 : t6; t7 = pop ? -__builtin_inff() : t7; }

__global__ __launch_bounds__(256) void cand_kernel(const u16* __restrict__ S2,
        u16* __restrict__ cand, int* __restrict__ ccnt) {
    __shared__ int scnt[4];
    int w    = threadIdx.x >> 6;
    int lane = threadIdx.x & 63;
    int row  = blockIdx.x * 4 + w;
    if (lane == 0) scnt[w] = 0;
    __syncthreads();

    const uint4* p = (const uint4*)(S2 + (size_t)row * NM);
    uint4 v[4];
    float t0 = -__builtin_inff(), t1 = t0, t2 = t0, t3 = t0, t4 = t0, t5 = t0, t6 = t0, t7 = t0;
    #pragma unroll
    for (int it = 0; it < 4; ++it) {
        v[it] = p[it * 64 + lane];
        const u32* d = (const u32*)&v[it];
        #pragma unroll
        for (int j = 0; j < 4; ++j) {
            INS(bf2f(d[j] & 0xFFFFu));
            INS(bf2f(d[j] >> 16));
        }
    }
    float g0, g1, g2, g3, g4, g5, g6, g7;
    ROUND(g0); ROUND(g1); ROUND(g2); ROUND(g3);
    ROUND(g4); ROUND(g5); ROUND(g6); ROUND(g7);
    (void)g0; (void)g1; (void)g2; (void)g3; (void)g4; (void)g5; (void)g6;
    float T = g7 - MARGIN;   // dup-pops only lower T -> safe (more candidates)

    #pragma unroll
    for (int it = 0; it < 4; ++it) {
        const u32* d = (const u32*)&v[it];
        #pragma unroll
        for (int j = 0; j < 4; ++j) {
            float flo = bf2f(d[j] & 0xFFFFu);
            float fhi = bf2f(d[j] >> 16);
            int   col = it * 512 + lane * 8 + j * 2;
            if (flo >= T) {
                int pos = atomicAdd(&scnt[w], 1);
                if (pos < CMAX) cand[(size_t)row * CMAX + pos] = (u16)col;
            }
            if (fhi >= T) {
                int pos = atomicAdd(&scnt[w], 1);
                if (pos < CMAX) cand[(size_t)row * CMAX + pos] = (u16)(col + 1);
            }
        }
    }
    __syncthreads();
    if (lane == 0) ccnt[row] = min(scnt[w], CMAX);
}

// ---------------- fp64 refine: exact top-8, f, g, winner counts ----------------
__global__ __launch_bounds__(256) void refine_kernel(const float* __restrict__ x,
        const float* __restrict__ K, const double* __restrict__ invKn,
        const u16* __restrict__ cand, const int* __restrict__ ccnt,
        float* __restrict__ top8v, u16* __restrict__ top8i,
        float* __restrict__ f_out, float* __restrict__ g_out, float* __restrict__ counts) {
    int row  = blockIdx.x * 4 + (threadIdx.x >> 6);
    int lane = threadIdx.x & 63;

    const float4* xr = (const float4*)(x + (size_t)row * ND);
    float4 a = xr[lane * 2], b = xr[lane * 2 + 1];
    double x0 = a.x, x1 = a.y, x2 = a.z, x3 = a.w;
    double x4 = b.x, x5 = b.y, x6 = b.z, x7 = b.w;

    double ss = x0*x0 + x1*x1 + x2*x2 + x3*x3 + x4*x4 + x5*x5 + x6*x6 + x7*x7;
    #pragma unroll
    for (int off = 1; off < 64; off <<= 1) ss += __shfl_xor(ss, off, 64);
    double xinv = 1.0 / fmax(sqrt(ss), 1e-12);

    int cnt = ccnt[row];
    int myidx = (lane < cnt) ? (int)cand[(size_t)row * CMAX + lane] : 0;
    double myval = -1e300;

    for (int c = 0; c < cnt; ++c) {
        int ci = __shfl(myidx, c, 64);
        const float4* kr = (const float4*)(K + (size_t)ci * ND);
        float4 k0 = kr[lane * 2], k1 = kr[lane * 2 + 1];
        double acc;
        acc = x0 * (double)k0.x;
        acc = fma(x1, (double)k0.y, acc);
        acc = fma(x2, (double)k0.z, acc);
        acc = fma(x3, (double)k0.w, acc);
        acc = fma(x4, (double)k1.x, acc);
        acc = fma(x5, (double)k1.y, acc);
        acc = fma(x6, (double)k1.z, acc);
        acc = fma(x7, (double)k1.w, acc);
        #pragma unroll
        for (int off = 1; off < 64; off <<= 1) acc += __shfl_xor(acc, off, 64);
        double val = acc * xinv * invKn[ci];
        if (lane == c) myval = val;
    }

    float vals[8]; int idxs[8];
    #pragma unroll
    for (int r = 0; r < 8; ++r) {
        double m = myval;
        #pragma unroll
        for (int off = 1; off < 64; off <<= 1) m = fmax(m, __shfl_xor(m, off, 64));
        unsigned long long bal = __ballot(myval == m);
        int wl = __ffsll(bal) - 1;
        int wi = __shfl(myidx, wl, 64);
        vals[r] = (float)m;
        idxs[r] = wi;
        if (lane == wl) myval = -1e300;
    }

    if (lane == 0) {
        float fv = vals[0];
        f_out[row] = fv;
        g_out[row] = 1.0f / (1.0f + expf(FBETA * (fv - FTHETA)));
        atomicAdd(&counts[idxs[0]], 1.0f);
        float4* tv = (float4*)(top8v + (size_t)row * 8);
        tv[0] = (float4){vals[0], vals[1], vals[2], vals[3]};
        tv[1] = (float4){vals[4], vals[5], vals[6], vals[7]};
        uint4 ip;
        ip.x = (u32)idxs[0] | ((u32)idxs[1] << 16);
        ip.y = (u32)idxs[2] | ((u32)idxs[3] << 16);
        ip.z = (u32)idxs[4] | ((u32)idxs[5] << 16);
        ip.w = (u32)idxs[6] | ((u32)idxs[7] << 16);
        *(uint4*)(top8i + (size_t)row * 8) = ip;
    }
}

// ---------------- finalize: softmax(8), attn row (zeros+scatter), y = g * attn@V ----------------
__global__ __launch_bounds__(256) void finalize_kernel(const float* __restrict__ top8v,
        const u16* __restrict__ top8i, const float* __restrict__ counts,
        const float* __restrict__ logs, const float* __restrict__ V,
        const float* __restrict__ g_out, float* __restrict__ y, float* __restrict__ attn) {
    int row  = blockIdx.x * 4 + (threadIdx.x >> 6);
    int lane = threadIdx.x & 63;
    float4 z = {0.f, 0.f, 0.f, 0.f};
    float4* arow = (float4*)(attn + (size_t)row * NM);
    #pragma unroll
    for (int i = 0; i < 8; i++) arow[i * 64 + lane] = z;

    float logit = -__builtin_inff();
    int idx = 0;
    if (lane < 8) {
        idx = (int)top8i[(size_t)row * 8 + lane];
        float val = top8v[(size_t)row * 8 + lane];
        logit = val * TAUINV + logs[idx] - (FGAMMA / (float)NB) * counts[idx];
    }
    float mv = logit;
    mv = fmaxf(mv, __shfl_xor(mv, 1, 64));
    mv = fmaxf(mv, __shfl_xor(mv, 2, 64));
    mv = fmaxf(mv, __shfl_xor(mv, 4, 64));
    float e = (lane < 8) ? expf(logit - mv) : 0.0f;
    float sum = e;
    sum += __shfl_xor(sum, 1, 64);
    sum += __shfl_xor(sum, 2, 64);
    sum += __shfl_xor(sum, 4, 64);
    float w = e / sum;   // garbage on lanes >=8, never consumed

    asm volatile("s_waitcnt vmcnt(0)" ::: "memory");
    if (lane < 8) attn[(size_t)row * NM + idx] = w;

    float4 acc0 = z, acc1 = z;
    #pragma unroll
    for (int j = 0; j < 8; j++) {
        float wj = __shfl(w, j, 64);
        int   ij = __shfl(idx, j, 64);
        const float4* vr = (const float4*)(V + (size_t)ij * 512);
        float4 v0 = vr[lane * 2], v1 = vr[lane * 2 + 1];
        acc0.x += wj * v0.x; acc0.y += wj * v0.y; acc0.z += wj * v0.z; acc0.w += wj * v0.w;
        acc1.x += wj * v1.x; acc1.y += wj * v1.y; acc1.z += wj * v1.z; acc1.w += wj * v1.w;
    }
    float gr = g_out[row];
    float4 o0 = {gr * acc0.x, gr * acc0.y, gr * acc0.z, gr * acc0.w};
    float4 o1 = {gr * acc1.x, gr * acc1.y, gr * acc1.z, gr * acc1.w};
    float4* yp = (float4*)(y + (size_t)row * 512);
    yp[lane * 2]     = o0;
    yp[lane * 2 + 1] = o1;
}

extern "C" void kernel_launch(void* const* d_in, const int* in_sizes, int n_in,
                              void* d_out, int out_size, void* d_ws, size_t ws_size,
                              hipStream_t stream) {
    const float* x = (const float*)d_in[0];
    const float* K = (const float*)d_in[1];
    const float* V = (const float*)d_in[2];
    const float* s = (const float*)d_in[3];

    float* y     = (float*)d_out;                       // [32768][512]
    float* f_out = y + (size_t)NB * 512;                // [32768]
    float* g_out = f_out + NB;                          // [32768]
    float* attn  = g_out + NB;                          // [32768][2048]

    char* ws = (char*)d_ws;
    u16*    xn     = (u16*)ws;                          // 33,554,432 B
    u16*    kn     = (u16*)(ws + 33554432);             //  2,097,152 B -> 35,651,584
    float*  logs   = (float*)(ws + 35651584);           //      8,192 B -> 35,659,776
    float*  counts = (float*)(ws + 35659776);           //      8,192 B -> 35,667,968
    double* invKn  = (double*)(ws + 35667968);          //     16,384 B -> 35,684,352
    float*  top8v  = (float*)(ws + 35684352);           //  1,048,576 B -> 36,732,928
    u16*    top8i  = (u16*)(ws + 36732928);             //    524,288 B -> 37,257,216
    int*    ccnt   = (int*)(ws + 37257216);             //    131,072 B -> 37,388,288
    u16*    cand   = (u16*)(ws + 37388288);             //  2,097,152 B -> 39,485,440
    u16*    S2     = (u16*)(ws + 67108864);             // 134,217,728 B bf16 scores

    rownorm_kernel<<<NB / 4, 256, 0, stream>>>(x, xn);
    kprep_kernel<<<NM / 4, 256, 0, stream>>>(K, kn, invKn, s, logs, counts);
    gemm_kernel<<<4096, 256, 0, stream>>>(xn, kn, S2);
    cand_kernel<<<NB / 4, 256, 0, stream>>>(S2, cand, ccnt);
    refine_kernel<<<NB / 4, 256, 0, stream>>>(x, K, invKn, cand, ccnt,
                                              top8v, top8i, f_out, g_out, counts);
    finalize_kernel<<<NB / 4, 256, 0, stream>>>(top8v, top8i, counts, logs, V,
                                                g_out, y, attn);
}

// Round 5
// 335.217 us; speedup vs baseline: 1.1618x; 1.0719x over previous
//
#include <hip/hip_runtime.h>
#include <math.h>

typedef unsigned short u16;
typedef unsigned int   u32;

#define NB     32768   // batch rows
#define ND     512     // d_in
#define NM     2048    // memory slots
#define TAUINV 10.0f
#define FBETA  10.0f
#define FTHETA 0.5f
#define FGAMMA 0.5f
#define CMAX   32      // candidate cap per row
#define MARGIN 3e-3f   // covers bf16-gemm err + bf16-S rounding

typedef __bf16 bf16x8 __attribute__((ext_vector_type(8)));
typedef float  f32x4  __attribute__((ext_vector_type(4)));

__device__ __forceinline__ u16 f2bf(float x) {
    u32 b = __float_as_uint(x);
    u32 r = (b + 0x7FFFu + ((b >> 16) & 1u)) >> 16;   // RNE
    return (u16)r;
}
__device__ __forceinline__ float bf2f(u32 h) { return __uint_as_float(h << 16); }

// ---------------- x rows: L2-normalize (f32 -> bf16) ----------------
__global__ __launch_bounds__(256) void rownorm_kernel(const float* __restrict__ in,
                                                      u16* __restrict__ out) {
    int row  = blockIdx.x * 4 + (threadIdx.x >> 6);
    int lane = threadIdx.x & 63;
    const float4* p = (const float4*)(in + (size_t)row * ND);
    float4 a = p[lane * 2], b = p[lane * 2 + 1];
    float ss = a.x*a.x + a.y*a.y + a.z*a.z + a.w*a.w +
               b.x*b.x + b.y*b.y + b.z*b.z + b.w*b.w;
    #pragma unroll
    for (int off = 1; off < 64; off <<= 1) ss += __shfl_xor(ss, off, 64);
    float sc = 1.0f / fmaxf(sqrtf(ss), 1e-12f);
    uint4 o;
    o.x = (u32)f2bf(a.x*sc) | ((u32)f2bf(a.y*sc) << 16);
    o.y = (u32)f2bf(a.z*sc) | ((u32)f2bf(a.w*sc) << 16);
    o.z = (u32)f2bf(b.x*sc) | ((u32)f2bf(b.y*sc) << 16);
    o.w = (u32)f2bf(b.z*sc) | ((u32)f2bf(b.w*sc) << 16);
    ((uint4*)(out + (size_t)row * ND))[lane] = o;
}

// ---------------- K rows: bf16-normalize + fp64 inv-norm + logs + counts=0 ----------------
__global__ __launch_bounds__(256) void kprep_kernel(const float* __restrict__ K,
        u16* __restrict__ kn, double* __restrict__ invKn,
        const float* __restrict__ s, float* __restrict__ logs, float* __restrict__ counts) {
    int row  = blockIdx.x * 4 + (threadIdx.x >> 6);
    int lane = threadIdx.x & 63;
    const float4* p = (const float4*)(K + (size_t)row * ND);
    float4 a = p[lane * 2], b = p[lane * 2 + 1];
    double ss = (double)a.x*a.x + (double)a.y*a.y + (double)a.z*a.z + (double)a.w*a.w +
                (double)b.x*b.x + (double)b.y*b.y + (double)b.z*b.z + (double)b.w*b.w;
    #pragma unroll
    for (int off = 1; off < 64; off <<= 1) ss += __shfl_xor(ss, off, 64);
    double inv = 1.0 / fmax(sqrt(ss), 1e-12);
    float sc = (float)inv;
    uint4 o;
    o.x = (u32)f2bf(a.x*sc) | ((u32)f2bf(a.y*sc) << 16);
    o.y = (u32)f2bf(a.z*sc) | ((u32)f2bf(a.w*sc) << 16);
    o.z = (u32)f2bf(b.x*sc) | ((u32)f2bf(b.y*sc) << 16);
    o.w = (u32)f2bf(b.z*sc) | ((u32)f2bf(b.w*sc) << 16);
    ((uint4*)(kn + (size_t)row * ND))[lane] = o;
    if (lane == 0) {
        invKn[row]  = inv;
        logs[row]   = logf(s[row] + 1e-8f);
        counts[row] = 0.0f;
    }
}

// ---------------- GEMM: S2[r][c] (bf16) = Xn[r]·Kn[c] ----------------
// 2-phase dbuf, counted vmcnt + raw s_barrier. Every s_barrier is followed by
// sched_barrier(0): llvm.amdgcn.s.barrier is NOT a memory-motion fence, so
// without it the next tile's global_load_lds (overwriting the buffer other
// waves still read) hoists above the barrier -> LDS race (r4 failure).
#define BKT 64
#define NKT (ND / BKT)
__global__ __launch_bounds__(256) void gemm_kernel(const u16* __restrict__ Xn,
                                                   const u16* __restrict__ Kn,
                                                   u16* __restrict__ S2) {
    __shared__ u16 smem[4][8192];   // [0..1]=A dbuf, [2..3]=B dbuf; reused as repack tile
    const int tid  = threadIdx.x;
    const int lane = tid & 63;
    const int wid  = tid >> 6;
    const int wr = wid >> 1, wc = wid & 1;

    // XCD-bijective swizzle: 4096 blocks % 8 == 0
    int lin = blockIdx.x;
    int swz = (lin & 7) * 512 + (lin >> 3);
    const int rowA = (swz >> 4) * 128;   // 256 row-panels
    const int colB = (swz & 15) * 128;   // 16 col-panels

    f32x4 acc[4][4];
    #pragma unroll
    for (int m = 0; m < 4; m++)
        #pragma unroll
        for (int n = 0; n < 4; n++) acc[m][n] = (f32x4){0.f, 0.f, 0.f, 0.f};

    auto stage = [&](int buf, int kt) {
        #pragma unroll
        for (int i = 0; i < 4; i++) {
            int lo = (i * 256 + tid) * 16;   // byte offset in 16KB tile
            int r  = lo >> 7;                // 128 B per LDS row
            int cb = lo & 127;
            const char* ga = (const char*)(Xn + (size_t)(rowA + r) * ND + kt * BKT) + cb;
            __builtin_amdgcn_global_load_lds((const __attribute__((address_space(1))) void*)ga,
                (__attribute__((address_space(3))) void*)((char*)(&smem[buf][0]) + lo), 16, 0, 0);
            const char* gb = (const char*)(Kn + (size_t)(colB + r) * ND + kt * BKT) + cb;
            __builtin_amdgcn_global_load_lds((const __attribute__((address_space(1))) void*)gb,
                (__attribute__((address_space(3))) void*)((char*)(&smem[2 + buf][0]) + lo), 16, 0, 0);
        }
    };

    stage(0, 0);                     // 8 loads in flight (tile 0)
    int cur = 0;
    #pragma unroll
    for (int kt = 0; kt < NKT; ++kt) {
        if (kt + 1 < NKT) {
            stage(cur ^ 1, kt + 1);  // +8 loads (tile kt+1); 16 in flight
            // wait only for tile kt's 8 (oldest, in-order retirement);
            // tile kt+1's 8 stay in flight across the barrier
            asm volatile("s_waitcnt vmcnt(8)" ::: "memory");
        } else {
            asm volatile("s_waitcnt vmcnt(0)" ::: "memory");
        }
        __builtin_amdgcn_s_barrier();        // all waves' tile-kt loads landed
        __builtin_amdgcn_sched_barrier(0);   // pin: nothing hoists above the barrier
        #pragma unroll
        for (int ks = 0; ks < 2; ++ks) {
            const int kof = ks * 32 + (lane >> 4) * 8;
            bf16x8 af[4], bq[4];
            #pragma unroll
            for (int m = 0; m < 4; m++) {
                int r = wr * 64 + m * 16 + (lane & 15);
                af[m] = *(const bf16x8*)(&smem[cur][r * BKT + kof]);
            }
            #pragma unroll
            for (int n = 0; n < 4; n++) {
                int c = wc * 64 + n * 16 + (lane & 15);
                bq[n] = *(const bf16x8*)(&smem[2 + cur][c * BKT + kof]);
            }
            #pragma unroll
            for (int m = 0; m < 4; m++)
                #pragma unroll
                for (int n = 0; n < 4; n++)
                    acc[m][n] = __builtin_amdgcn_mfma_f32_16x16x32_bf16(af[m], bq[n], acc[m][n], 0, 0, 0);
        }
        asm volatile("" ::: "memory");
        __builtin_amdgcn_s_barrier();        // all waves done READING cur
        __builtin_amdgcn_sched_barrier(0);   // pin: next stage/epilogue can't hoist above
        cur ^= 1;
    }

    // epilogue: bf16-convert through LDS (pad 136 u16/row keeps 16B-aligned rows)
    u16* St = (u16*)&smem[0][0];   // 128 x 136 u16 = 34,816 B
    #pragma unroll
    for (int m = 0; m < 4; m++) {
        int rloc = wr * 64 + m * 16 + (lane >> 4) * 4;
        #pragma unroll
        for (int n = 0; n < 4; n++) {
            int cloc = wc * 64 + n * 16 + (lane & 15);
            #pragma unroll
            for (int j = 0; j < 4; j++)
                St[(rloc + j) * 136 + cloc] = f2bf(acc[m][n][j]);
        }
    }
    __syncthreads();
    int c16 = tid & 15;
    #pragma unroll
    for (int i = 0; i < 8; i++) {
        int r = i * 16 + (tid >> 4);
        uint4 val = *(const uint4*)(St + r * 136 + c16 * 8);
        *(uint4*)(S2 + (size_t)(rowA + r) * NM + colB + c16 * 8) = val;
    }
}

// ---------------- fused candidate-select + fp64 refine (one wave per row) ----------------
#define INS(VV) { float x_ = (VV); float h_;                      \
    h_ = fmaxf(t0, x_); x_ = fminf(t0, x_); t0 = h_;              \
    h_ = fmaxf(t1, x_); x_ = fminf(t1, x_); t1 = h_;              \
    h_ = fmaxf(t2, x_); x_ = fminf(t2, x_); t2 = h_;              \
    h_ = fmaxf(t3, x_); x_ = fminf(t3, x_); t3 = h_;              \
    h_ = fmaxf(t4, x_); x_ = fminf(t4, x_); t4 = h_;              \
    h_ = fmaxf(t5, x_); x_ = fminf(t5, x_); t5 = h_;              \
    h_ = fmaxf(t6, x_); x_ = fminf(t6, x_); t6 = h_;              \
    h_ = fmaxf(t7, x_); x_ = fminf(t7, x_); t7 = h_; }

#define ROUND(G) {                                                \
    float mv = t0;                                                \
    mv = fmaxf(mv, __shfl_xor(mv, 1, 64));                        \
    mv = fmaxf(mv, __shfl_xor(mv, 2, 64));                        \
    mv = fmaxf(mv, __shfl_xor(mv, 4, 64));                        \
    mv = fmaxf(mv, __shfl_xor(mv, 8, 64));                        \
    mv = fmaxf(mv, __shfl_xor(mv, 16, 64));                       \
    mv = fmaxf(mv, __shfl_xor(mv, 32, 64));                       \
    G = mv;                                                       \
    bool pop = (t0 == mv);                                        \
    t0 = pop ? t1 : t0; t1 = pop ? t2 : t1; t2 = pop ? t3 : t2;   \
    t3 = pop ? t4 : t3; t4 = pop ? t5 : t4; t5 = pop ? t6 : t5;   \
    t6 = pop ? t7 : t6; t7 = pop ? -__builtin_inff() : t7; }

__global__ __launch_bounds__(256) void candrefine_kernel(const u16* __restrict__ S2,
        const float* __restrict__ x, const float* __restrict__ K,
        const double* __restrict__ invKn,
        float* __restrict__ top8v, u16* __restrict__ top8i,
        float* __restrict__ f_out, float* __restrict__ g_out, float* __restrict__ counts) {
    __shared__ u16 candl[4][CMAX];
    __shared__ int scnt[4];
    int w    = threadIdx.x >> 6;
    int lane = threadIdx.x & 63;
    int row  = blockIdx.x * 4 + w;
    if (lane == 0) scnt[w] = 0;
    asm volatile("s_waitcnt lgkmcnt(0)" ::: "memory");

    // ---- phase A: candidate selection from bf16 S (wave-local) ----
    {
        const uint4* p = (const uint4*)(S2 + (size_t)row * NM);
        uint4 v[4];
        float t0 = -__builtin_inff(), t1 = t0, t2 = t0, t3 = t0, t4 = t0, t5 = t0, t6 = t0, t7 = t0;
        #pragma unroll
        for (int it = 0; it < 4; ++it) {
            v[it] = p[it * 64 + lane];
            const u32* d = (const u32*)&v[it];
            #pragma unroll
            for (int j = 0; j < 4; ++j) {
                INS(bf2f(d[j] & 0xFFFFu));
                INS(bf2f(d[j] >> 16));
            }
        }
        float g0, g1, g2, g3, g4, g5, g6, g7;
        ROUND(g0); ROUND(g1); ROUND(g2); ROUND(g3);
        ROUND(g4); ROUND(g5); ROUND(g6); ROUND(g7);
        (void)g0; (void)g1; (void)g2; (void)g3; (void)g4; (void)g5; (void)g6;
        float T = g7 - MARGIN;   // dup-pops only lower T -> safe (more candidates)

        #pragma unroll
        for (int it = 0; it < 4; ++it) {
            const u32* d = (const u32*)&v[it];
            #pragma unroll
            for (int j = 0; j < 4; ++j) {
                float flo = bf2f(d[j] & 0xFFFFu);
                float fhi = bf2f(d[j] >> 16);
                int   col = it * 512 + lane * 8 + j * 2;
                if (flo >= T) {
                    int pos = atomicAdd(&scnt[w], 1);
                    if (pos < CMAX) candl[w][pos] = (u16)col;
                }
                if (fhi >= T) {
                    int pos = atomicAdd(&scnt[w], 1);
                    if (pos < CMAX) candl[w][pos] = (u16)(col + 1);
                }
            }
        }
    }
    asm volatile("s_waitcnt lgkmcnt(0)" ::: "memory");

    // ---- phase B: fp64 exact rescore of candidates ----
    const float4* xr = (const float4*)(x + (size_t)row * ND);
    float4 a = xr[lane * 2], b = xr[lane * 2 + 1];
    double x0 = a.x, x1 = a.y, x2 = a.z, x3 = a.w;
    double x4 = b.x, x5 = b.y, x6 = b.z, x7 = b.w;

    double ss = x0*x0 + x1*x1 + x2*x2 + x3*x3 + x4*x4 + x5*x5 + x6*x6 + x7*x7;
    #pragma unroll
    for (int off = 1; off < 64; off <<= 1) ss += __shfl_xor(ss, off, 64);
    double xinv = 1.0 / fmax(sqrt(ss), 1e-12);

    int cnt = min(scnt[w], CMAX);
    int myidx = (lane < cnt) ? (int)candl[w][lane] : 0;
    double myval = -1e300;

    for (int c = 0; c < cnt; ++c) {
        int ci = __shfl(myidx, c, 64);
        const float4* kr = (const float4*)(K + (size_t)ci * ND);
        float4 k0 = kr[lane * 2], k1 = kr[lane * 2 + 1];
        double acc;
        acc = x0 * (double)k0.x;
        acc = fma(x1, (double)k0.y, acc);
        acc = fma(x2, (double)k0.z, acc);
        acc = fma(x3, (double)k0.w, acc);
        acc = fma(x4, (double)k1.x, acc);
        acc = fma(x5, (double)k1.y, acc);
        acc = fma(x6, (double)k1.z, acc);
        acc = fma(x7, (double)k1.w, acc);
        #pragma unroll
        for (int off = 1; off < 64; off <<= 1) acc += __shfl_xor(acc, off, 64);
        double val = acc * xinv * invKn[ci];
        if (lane == c) myval = val;
    }

    float vals[8]; int idxs[8];
    #pragma unroll
    for (int r = 0; r < 8; ++r) {
        double m = myval;
        #pragma unroll
        for (int off = 1; off < 64; off <<= 1) m = fmax(m, __shfl_xor(m, off, 64));
        unsigned long long bal = __ballot(myval == m);
        int wl = __ffsll(bal) - 1;
        int wi = __shfl(myidx, wl, 64);
        vals[r] = (float)m;
        idxs[r] = wi;
        if (lane == wl) myval = -1e300;
    }

    if (lane == 0) {
        float fv = vals[0];
        f_out[row] = fv;
        g_out[row] = 1.0f / (1.0f + expf(FBETA * (fv - FTHETA)));
        atomicAdd(&counts[idxs[0]], 1.0f);
        float4* tv = (float4*)(top8v + (size_t)row * 8);
        tv[0] = (float4){vals[0], vals[1], vals[2], vals[3]};
        tv[1] = (float4){vals[4], vals[5], vals[6], vals[7]};
        uint4 ip;
        ip.x = (u32)idxs[0] | ((u32)idxs[1] << 16);
        ip.y = (u32)idxs[2] | ((u32)idxs[3] << 16);
        ip.z = (u32)idxs[4] | ((u32)idxs[5] << 16);
        ip.w = (u32)idxs[6] | ((u32)idxs[7] << 16);
        *(uint4*)(top8i + (size_t)row * 8) = ip;
    }
}

// ---------------- finalize: softmax(8), attn row (zeros+scatter), y = g * attn@V ----------------
__global__ __launch_bounds__(256) void finalize_kernel(const float* __restrict__ top8v,
        const u16* __restrict__ top8i, const float* __restrict__ counts,
        const float* __restrict__ logs, const float* __restrict__ V,
        const float* __restrict__ g_out, float* __restrict__ y, float* __restrict__ attn) {
    int row  = blockIdx.x * 4 + (threadIdx.x >> 6);
    int lane = threadIdx.x & 63;
    float4 z = {0.f, 0.f, 0.f, 0.f};
    float4* arow = (float4*)(attn + (size_t)row * NM);
    #pragma unroll
    for (int i = 0; i < 8; i++) arow[i * 64 + lane] = z;

    float logit = -__builtin_inff();
    int idx = 0;
    if (lane < 8) {
        idx = (int)top8i[(size_t)row * 8 + lane];
        float val = top8v[(size_t)row * 8 + lane];
        logit = val * TAUINV + logs[idx] - (FGAMMA / (float)NB) * counts[idx];
    }
    float mv = logit;
    mv = fmaxf(mv, __shfl_xor(mv, 1, 64));
    mv = fmaxf(mv, __shfl_xor(mv, 2, 64));
    mv = fmaxf(mv, __shfl_xor(mv, 4, 64));
    float e = (lane < 8) ? expf(logit - mv) : 0.0f;
    float sum = e;
    sum += __shfl_xor(sum, 1, 64);
    sum += __shfl_xor(sum, 2, 64);
    sum += __shfl_xor(sum, 4, 64);
    float w = e / sum;   // garbage on lanes >=8, never consumed

    asm volatile("s_waitcnt vmcnt(0)" ::: "memory");
    if (lane < 8) attn[(size_t)row * NM + idx] = w;

    float4 acc0 = z, acc1 = z;
    #pragma unroll
    for (int j = 0; j < 8; j++) {
        float wj = __shfl(w, j, 64);
        int   ij = __shfl(idx, j, 64);
        const float4* vr = (const float4*)(V + (size_t)ij * 512);
        float4 v0 = vr[lane * 2], v1 = vr[lane * 2 + 1];
        acc0.x += wj * v0.x; acc0.y += wj * v0.y; acc0.z += wj * v0.z; acc0.w += wj * v0.w;
        acc1.x += wj * v1.x; acc1.y += wj * v1.y; acc1.z += wj * v1.z; acc1.w += wj * v1.w;
    }
    float gr = g_out[row];
    float4 o0 = {gr * acc0.x, gr * acc0.y, gr * acc0.z, gr * acc0.w};
    float4 o1 = {gr * acc1.x, gr * acc1.y, gr * acc1.z, gr * acc1.w};
    float4* yp = (float4*)(y + (size_t)row * 512);
    yp[lane * 2]     = o0;
    yp[lane * 2 + 1] = o1;
}

extern "C" void kernel_launch(void* const* d_in, const int* in_sizes, int n_in,
                              void* d_out, int out_size, void* d_ws, size_t ws_size,
                              hipStream_t stream) {
    const float* x = (const float*)d_in[0];
    const float* K = (const float*)d_in[1];
    const float* V = (const float*)d_in[2];
    const float* s = (const float*)d_in[3];

    float* y     = (float*)d_out;                       // [32768][512]
    float* f_out = y + (size_t)NB * 512;                // [32768]
    float* g_out = f_out + NB;                          // [32768]
    float* attn  = g_out + NB;                          // [32768][2048]

    char* ws = (char*)d_ws;
    u16*    xn     = (u16*)ws;                          // 33,554,432 B
    u16*    kn     = (u16*)(ws + 33554432);             //  2,097,152 B -> 35,651,584
    float*  logs   = (float*)(ws + 35651584);           //      8,192 B -> 35,659,776
    float*  counts = (float*)(ws + 35659776);           //      8,192 B -> 35,667,968
    double* invKn  = (double*)(ws + 35667968);          //     16,384 B -> 35,684,352
    float*  top8v  = (float*)(ws + 35684352);           //  1,048,576 B -> 36,732,928
    u16*    top8i  = (u16*)(ws + 36732928);             //    524,288 B -> 37,257,216
    u16*    S2     = (u16*)(ws + 67108864);             // 134,217,728 B bf16 scores

    rownorm_kernel<<<NB / 4, 256, 0, stream>>>(x, xn);
    kprep_kernel<<<NM / 4, 256, 0, stream>>>(K, kn, invKn, s, logs, counts);
    gemm_kernel<<<4096, 256, 0, stream>>>(xn, kn, S2);
    candrefine_kernel<<<NB / 4, 256, 0, stream>>>(S2, x, K, invKn,
                                                  top8v, top8i, f_out, g_out, counts);
    finalize_kernel<<<NB / 4, 256, 0, stream>>>(top8v, top8i, counts, logs, V,
                                                g_out, y, attn);
}

// Round 6
// 327.707 us; speedup vs baseline: 1.1884x; 1.0229x over previous
//
#include <hip/hip_runtime.h>
#include <math.h>

typedef unsigned short u16;
typedef unsigned int   u32;

#define NB     32768   // batch rows
#define ND     512     // d_in
#define NM     2048    // memory slots
#define TAUINV 10.0f
#define FBETA  10.0f
#define FTHETA 0.5f
#define FGAMMA 0.5f
#define CMAX   32      // candidate cap per row
#define MARGIN 3e-3f   // covers bf16-gemm err + bf16-S rounding

typedef __bf16 bf16x8 __attribute__((ext_vector_type(8)));
typedef float  f32x4  __attribute__((ext_vector_type(4)));

__device__ __forceinline__ u16 f2bf(float x) {
    u32 b = __float_as_uint(x);
    u32 r = (b + 0x7FFFu + ((b >> 16) & 1u)) >> 16;   // RNE
    return (u16)r;
}
__device__ __forceinline__ float bf2f(u32 h) { return __uint_as_float(h << 16); }

// ---------------- x rows: L2-normalize (f32 -> bf16) ----------------
__global__ __launch_bounds__(256) void rownorm_kernel(const float* __restrict__ in,
                                                      u16* __restrict__ out) {
    int row  = blockIdx.x * 4 + (threadIdx.x >> 6);
    int lane = threadIdx.x & 63;
    const float4* p = (const float4*)(in + (size_t)row * ND);
    float4 a = p[lane * 2], b = p[lane * 2 + 1];
    float ss = a.x*a.x + a.y*a.y + a.z*a.z + a.w*a.w +
               b.x*b.x + b.y*b.y + b.z*b.z + b.w*b.w;
    #pragma unroll
    for (int off = 1; off < 64; off <<= 1) ss += __shfl_xor(ss, off, 64);
    float sc = 1.0f / fmaxf(sqrtf(ss), 1e-12f);
    uint4 o;
    o.x = (u32)f2bf(a.x*sc) | ((u32)f2bf(a.y*sc) << 16);
    o.y = (u32)f2bf(a.z*sc) | ((u32)f2bf(a.w*sc) << 16);
    o.z = (u32)f2bf(b.x*sc) | ((u32)f2bf(b.y*sc) << 16);
    o.w = (u32)f2bf(b.z*sc) | ((u32)f2bf(b.w*sc) << 16);
    ((uint4*)(out + (size_t)row * ND))[lane] = o;
}

// ---------------- K rows: bf16-normalize + fp64 inv-norm + logs + counts=0 ----------------
__global__ __launch_bounds__(256) void kprep_kernel(const float* __restrict__ K,
        u16* __restrict__ kn, double* __restrict__ invKn,
        const float* __restrict__ s, float* __restrict__ logs, float* __restrict__ counts) {
    int row  = blockIdx.x * 4 + (threadIdx.x >> 6);
    int lane = threadIdx.x & 63;
    const float4* p = (const float4*)(K + (size_t)row * ND);
    float4 a = p[lane * 2], b = p[lane * 2 + 1];
    double ss = (double)a.x*a.x + (double)a.y*a.y + (double)a.z*a.z + (double)a.w*a.w +
                (double)b.x*b.x + (double)b.y*b.y + (double)b.z*b.z + (double)b.w*b.w;
    #pragma unroll
    for (int off = 1; off < 64; off <<= 1) ss += __shfl_xor(ss, off, 64);
    double inv = 1.0 / fmax(sqrt(ss), 1e-12);
    float sc = (float)inv;
    uint4 o;
    o.x = (u32)f2bf(a.x*sc) | ((u32)f2bf(a.y*sc) << 16);
    o.y = (u32)f2bf(a.z*sc) | ((u32)f2bf(a.w*sc) << 16);
    o.z = (u32)f2bf(b.x*sc) | ((u32)f2bf(b.y*sc) << 16);
    o.w = (u32)f2bf(b.z*sc) | ((u32)f2bf(b.w*sc) << 16);
    ((uint4*)(kn + (size_t)row * ND))[lane] = o;
    if (lane == 0) {
        invKn[row]  = inv;
        logs[row]   = logf(s[row] + 1e-8f);
        counts[row] = 0.0f;
    }
}

// ---------------- GEMM: 256x256 tile, 8-wave, 8-phase lockstep, swizzled LDS ----------------
// A LDS: [dbuf2][half2][128 rows][64 k] bf16 @ smem[0..64K); B same @ smem[64K..128K).
// Swizzle: physical kbyte = kb ^ ((row&7)<<4)  (bijective per row; read-side and
// inverse-swizzled global source agree; global_load_lds dest stays linear).
#define GLDS(SRC, OFF) __builtin_amdgcn_global_load_lds( \
    (const __attribute__((address_space(1))) void*)(SRC), \
    (__attribute__((address_space(3))) void*)(smem_c + (OFF)), 16, 0, 0)

#define STAGE8(KTN, D) { \
    _Pragma("unroll") for (int u_ = 0; u_ < 4; ++u_) { \
        _Pragma("unroll") for (int i_ = 0; i_ < 2; ++i_) { \
            int li_ = i_ * 512 + tid; \
            int rl_ = li_ >> 3; \
            int kb_ = ((li_ & 7) * 16) ^ ((rl_ & 7) << 4); \
            const char* src_ = (u_ < 2) \
                ? (const char*)Xn + (((size_t)(rowA + u_ * 128 + rl_)) << 10) + (KTN) * 128 + kb_ \
                : (const char*)Kn + (((size_t)(colB + (u_ - 2) * 128 + rl_)) << 10) + (KTN) * 128 + kb_; \
            GLDS(src_, (u_ < 2 ? 0 : 65536) + (D) * 32768 + (u_ & 1) * 16384 + li_ * 16); \
        } \
    } \
}

#define PHASE(AOFF, BOFF, P) { \
    const int ks_ = (P) >> 1, m4_ = ((P) & 1) * 4; \
    if (((P) & 1) == 0) { \
        _Pragma("unroll") for (int n_ = 0; n_ < 4; ++n_) \
            bq[n_] = *(const bf16x8*)(smem_c + (BOFF) + \
                ((wcl * 64 + n_ * 16 + lo) * 128) + ((ks_ * 64 + hb) ^ swzc)); \
    } \
    _Pragma("unroll") for (int mm_ = 0; mm_ < 4; ++mm_) \
        af[mm_] = *(const bf16x8*)(smem_c + (AOFF) + \
            (((m4_ + mm_) * 16 + lo) * 128) + ((ks_ * 64 + hb) ^ swzc)); \
    __builtin_amdgcn_s_barrier(); \
    __builtin_amdgcn_sched_barrier(0); \
    asm volatile("s_waitcnt lgkmcnt(0)" ::: "memory"); \
    __builtin_amdgcn_sched_barrier(0); \
    __builtin_amdgcn_s_setprio(1); \
    _Pragma("unroll") for (int mm_ = 0; mm_ < 4; ++mm_) \
        _Pragma("unroll") for (int n_ = 0; n_ < 4; ++n_) \
            acc[m4_ + mm_][n_] = __builtin_amdgcn_mfma_f32_16x16x32_bf16( \
                af[mm_], bq[n_], acc[m4_ + mm_][n_], 0, 0, 0); \
    __builtin_amdgcn_s_setprio(0); \
    __builtin_amdgcn_sched_barrier(0); \
    __builtin_amdgcn_s_barrier(); \
    __builtin_amdgcn_sched_barrier(0); \
}

// One K-tile: counted vmcnt at top (retire exactly the K-tile we are about to
// read; keep the next K-tile's 8 loads in flight). Stage kt+2 only after the
// phase-3 trailing barrier (all waves provably done reading buf[CUR]).
#define TILE(KT, CUR, LASTVM, DOSTAGE) { \
    if (LASTVM) { asm volatile("s_waitcnt vmcnt(0)" ::: "memory"); } \
    else        { asm volatile("s_waitcnt vmcnt(8)" ::: "memory"); } \
    __builtin_amdgcn_s_barrier(); \
    __builtin_amdgcn_sched_barrier(0); \
    bf16x8 af[4], bq[4]; \
    const int aO_ = (CUR) * 32768 + wr * 16384; \
    const int bO_ = 65536 + (CUR) * 32768 + bh * 16384; \
    PHASE(aO_, bO_, 0) \
    PHASE(aO_, bO_, 1) \
    PHASE(aO_, bO_, 2) \
    PHASE(aO_, bO_, 3) \
    if (DOSTAGE) STAGE8((KT) + 2, CUR); \
}

__global__ __launch_bounds__(512, 2) void gemm_kernel(const u16* __restrict__ Xn,
                                                      const u16* __restrict__ Kn,
                                                      u16* __restrict__ S2) {
    __shared__ u16 smem[65536];   // 128 KiB
    char* smem_c = (char*)smem;
    const int tid  = threadIdx.x;
    const int lane = tid & 63;
    const int wid  = tid >> 6;          // 0..7
    const int wr   = wid >> 2;          // 0..1  (M)
    const int wc   = wid & 3;           // 0..3  (N)
    const int wcl  = wc & 1;
    const int bh   = wc >> 1;
    const int lo   = lane & 15;
    const int hb   = (lane >> 4) * 16;  // k-slot byte within 64B k-slice
    const int swzc = (lo & 7) << 4;

    // XCD-bijective swizzle: 1024 blocks % 8 == 0; 8 consecutive per-XCD blocks
    // share the same A row-panel (L2 reuse), B (2 MB) is L2-resident per XCD.
    int lin = blockIdx.x;
    int swz = (lin & 7) * 128 + (lin >> 3);
    const int rowA = (swz >> 3) * 256;   // 128 row-panels
    const int colB = (swz & 7) * 256;    // 8 col-panels

    f32x4 acc[8][4];
    #pragma unroll
    for (int m = 0; m < 8; m++)
        #pragma unroll
        for (int n = 0; n < 4; n++) acc[m][n] = (f32x4){0.f, 0.f, 0.f, 0.f};

    STAGE8(0, 0);   // K-tile 0 -> buf0 (8 loads)
    STAGE8(1, 1);   // K-tile 1 -> buf1 (8 loads)

    for (int kt2 = 0; kt2 < 6; kt2 += 2) {
        TILE(kt2,     0, 0, 1)
        TILE(kt2 + 1, 1, 0, 1)
    }
    TILE(6, 0, 0, 0)
    TILE(7, 1, 1, 0)

    // epilogue: repack 256x256 fp32 acc -> bf16 via LDS, two 128-row passes
    u16* St = smem;                      // [128][264] u16 (row stride 528 B, 16B-aligned)
    #pragma unroll
    for (int h = 0; h < 2; ++h) {
        __syncthreads();
        if (wr == h) {
            #pragma unroll
            for (int m = 0; m < 8; m++) {
                int rloc = m * 16 + (lane >> 4) * 4;
                #pragma unroll
                for (int n = 0; n < 4; n++) {
                    int cloc = wc * 64 + n * 16 + lo;
                    #pragma unroll
                    for (int j = 0; j < 4; j++)
                        St[(rloc + j) * 264 + cloc] = f2bf(acc[m][n][j]);
                }
            }
        }
        __syncthreads();
        #pragma unroll
        for (int jj = 0; jj < 8; ++jj) {
            int idx = jj * 512 + tid;         // 0..4095
            int r = idx >> 5, sl = idx & 31;
            uint4 v = *(const uint4*)(St + (size_t)r * 264 + sl * 8);
            *(uint4*)(S2 + (size_t)(rowA + h * 128 + r) * NM + colB + sl * 8) = v;
        }
    }
}

// ---------------- fused candidate-select + fp64 refine (one wave per row) ----------------
#define INS(VV) { float x_ = (VV); float h_;                      \
    h_ = fmaxf(t0, x_); x_ = fminf(t0, x_); t0 = h_;              \
    h_ = fmaxf(t1, x_); x_ = fminf(t1, x_); t1 = h_;              \
    h_ = fmaxf(t2, x_); x_ = fminf(t2, x_); t2 = h_;              \
    h_ = fmaxf(t3, x_); x_ = fminf(t3, x_); t3 = h_;              \
    h_ = fmaxf(t4, x_); x_ = fminf(t4, x_); t4 = h_;              \
    h_ = fmaxf(t5, x_); x_ = fminf(t5, x_); t5 = h_;              \
    h_ = fmaxf(t6, x_); x_ = fminf(t6, x_); t6 = h_;              \
    h_ = fmaxf(t7, x_); x_ = fminf(t7, x_); t7 = h_; }

#define ROUND(G) {                                                \
    float mv = t0;                                                \
    mv = fmaxf(mv, __shfl_xor(mv, 1, 64));                        \
    mv = fmaxf(mv, __shfl_xor(mv, 2, 64));                        \
    mv = fmaxf(mv, __shfl_xor(mv, 4, 64));                        \
    mv = fmaxf(mv, __shfl_xor(mv, 8, 64));                        \
    mv = fmaxf(mv, __shfl_xor(mv, 16, 64));                       \
    mv = fmaxf(mv, __shfl_xor(mv, 32, 64));                       \
    G = mv;                                                       \
    bool pop = (t0 == mv);                                        \
    t0 = pop ? t1 : t0; t1 = pop ? t2 : t1; t2 = pop ? t3 : t2;   \
    t3 = pop ? t4 : t3; t4 = pop ? t5 : t4; t5 = pop ? t6 : t5;   \
    t6 = pop ? t7 : t6; t7 = pop ? -__builtin_inff() : t7; }

__global__ __launch_bounds__(256) void candrefine_kernel(const u16* __restrict__ S2,
        const float* __restrict__ x, const float* __restrict__ K,
        const double* __restrict__ invKn,
        float* __restrict__ top8v, u16* __restrict__ top8i,
        float* __restrict__ f_out, float* __restrict__ g_out, float* __restrict__ counts) {
    __shared__ u16 candl[4][CMAX];
    __shared__ int scnt[4];
    int w    = threadIdx.x >> 6;
    int lane = threadIdx.x & 63;
    int row  = blockIdx.x * 4 + w;
    if (lane == 0) scnt[w] = 0;
    asm volatile("s_waitcnt lgkmcnt(0)" ::: "memory");

    // ---- phase A: candidate selection from bf16 S (wave-local) ----
    {
        const uint4* p = (const uint4*)(S2 + (size_t)row * NM);
        uint4 v[4];
        float t0 = -__builtin_inff(), t1 = t0, t2 = t0, t3 = t0, t4 = t0, t5 = t0, t6 = t0, t7 = t0;
        #pragma unroll
        for (int it = 0; it < 4; ++it) {
            v[it] = p[it * 64 + lane];
            const u32* d = (const u32*)&v[it];
            #pragma unroll
            for (int j = 0; j < 4; ++j) {
                INS(bf2f(d[j] & 0xFFFFu));
                INS(bf2f(d[j] >> 16));
            }
        }
        float g0, g1, g2, g3, g4, g5, g6, g7;
        ROUND(g0); ROUND(g1); ROUND(g2); ROUND(g3);
        ROUND(g4); ROUND(g5); ROUND(g6); ROUND(g7);
        (void)g0; (void)g1; (void)g2; (void)g3; (void)g4; (void)g5; (void)g6;
        float T = g7 - MARGIN;   // dup-pops only lower T -> safe (more candidates)

        #pragma unroll
        for (int it = 0; it < 4; ++it) {
            const u32* d = (const u32*)&v[it];
            #pragma unroll
            for (int j = 0; j < 4; ++j) {
                float flo = bf2f(d[j] & 0xFFFFu);
                float fhi = bf2f(d[j] >> 16);
                int   col = it * 512 + lane * 8 + j * 2;
                if (flo >= T) {
                    int pos = atomicAdd(&scnt[w], 1);
                    if (pos < CMAX) candl[w][pos] = (u16)col;
                }
                if (fhi >= T) {
                    int pos = atomicAdd(&scnt[w], 1);
                    if (pos < CMAX) candl[w][pos] = (u16)(col + 1);
                }
            }
        }
    }
    asm volatile("s_waitcnt lgkmcnt(0)" ::: "memory");

    // ---- phase B: fp64 exact rescore of candidates ----
    const float4* xr = (const float4*)(x + (size_t)row * ND);
    float4 a = xr[lane * 2], b = xr[lane * 2 + 1];
    double x0 = a.x, x1 = a.y, x2 = a.z, x3 = a.w;
    double x4 = b.x, x5 = b.y, x6 = b.z, x7 = b.w;

    double ss = x0*x0 + x1*x1 + x2*x2 + x3*x3 + x4*x4 + x5*x5 + x6*x6 + x7*x7;
    #pragma unroll
    for (int off = 1; off < 64; off <<= 1) ss += __shfl_xor(ss, off, 64);
    double xinv = 1.0 / fmax(sqrt(ss), 1e-12);

    int cnt = min(scnt[w], CMAX);
    int myidx = (lane < cnt) ? (int)candl[w][lane] : 0;
    double myval = -1e300;

    for (int c = 0; c < cnt; ++c) {
        int ci = __shfl(myidx, c, 64);
        const float4* kr = (const float4*)(K + (size_t)ci * ND);
        float4 k0 = kr[lane * 2], k1 = kr[lane * 2 + 1];
        double acc;
        acc = x0 * (double)k0.x;
        acc = fma(x1, (double)k0.y, acc);
        acc = fma(x2, (double)k0.z, acc);
        acc = fma(x3, (double)k0.w, acc);
        acc = fma(x4, (double)k1.x, acc);
        acc = fma(x5, (double)k1.y, acc);
        acc = fma(x6, (double)k1.z, acc);
        acc = fma(x7, (double)k1.w, acc);
        #pragma unroll
        for (int off = 1; off < 64; off <<= 1) acc += __shfl_xor(acc, off, 64);
        double val = acc * xinv * invKn[ci];
        if (lane == c) myval = val;
    }

    float vals[8]; int idxs[8];
    #pragma unroll
    for (int r = 0; r < 8; ++r) {
        double m = myval;
        #pragma unroll
        for (int off = 1; off < 64; off <<= 1) m = fmax(m, __shfl_xor(m, off, 64));
        unsigned long long bal = __ballot(myval == m);
        int wl = __ffsll(bal) - 1;
        int wi = __shfl(myidx, wl, 64);
        vals[r] = (float)m;
        idxs[r] = wi;
        if (lane == wl) myval = -1e300;
    }

    if (lane == 0) {
        float fv = vals[0];
        f_out[row] = fv;
        g_out[row] = 1.0f / (1.0f + expf(FBETA * (fv - FTHETA)));
        atomicAdd(&counts[idxs[0]], 1.0f);
        float4* tv = (float4*)(top8v + (size_t)row * 8);
        tv[0] = (float4){vals[0], vals[1], vals[2], vals[3]};
        tv[1] = (float4){vals[4], vals[5], vals[6], vals[7]};
        uint4 ip;
        ip.x = (u32)idxs[0] | ((u32)idxs[1] << 16);
        ip.y = (u32)idxs[2] | ((u32)idxs[3] << 16);
        ip.z = (u32)idxs[4] | ((u32)idxs[5] << 16);
        ip.w = (u32)idxs[6] | ((u32)idxs[7] << 16);
        *(uint4*)(top8i + (size_t)row * 8) = ip;
    }
}

// ---------------- finalize: softmax(8), attn row (zeros+scatter), y = g * attn@V ----------------
__global__ __launch_bounds__(256) void finalize_kernel(const float* __restrict__ top8v,
        const u16* __restrict__ top8i, const float* __restrict__ counts,
        const float* __restrict__ logs, const float* __restrict__ V,
        const float* __restrict__ g_out, float* __restrict__ y, float* __restrict__ attn) {
    int row  = blockIdx.x * 4 + (threadIdx.x >> 6);
    int lane = threadIdx.x & 63;
    float4 z = {0.f, 0.f, 0.f, 0.f};
    float4* arow = (float4*)(attn + (size_t)row * NM);
    #pragma unroll
    for (int i = 0; i < 8; i++) arow[i * 64 + lane] = z;

    float logit = -__builtin_inff();
    int idx = 0;
    if (lane < 8) {
        idx = (int)top8i[(size_t)row * 8 + lane];
        float val = top8v[(size_t)row * 8 + lane];
        logit = val * TAUINV + logs[idx] - (FGAMMA / (float)NB) * counts[idx];
    }
    float mv = logit;
    mv = fmaxf(mv, __shfl_xor(mv, 1, 64));
    mv = fmaxf(mv, __shfl_xor(mv, 2, 64));
    mv = fmaxf(mv, __shfl_xor(mv, 4, 64));
    float e = (lane < 8) ? expf(logit - mv) : 0.0f;
    float sum = e;
    sum += __shfl_xor(sum, 1, 64);
    sum += __shfl_xor(sum, 2, 64);
    sum += __shfl_xor(sum, 4, 64);
    float w = e / sum;   // garbage on lanes >=8, never consumed

    asm volatile("s_waitcnt vmcnt(0)" ::: "memory");
    if (lane < 8) attn[(size_t)row * NM + idx] = w;

    float4 acc0 = z, acc1 = z;
    #pragma unroll
    for (int j = 0; j < 8; j++) {
        float wj = __shfl(w, j, 64);
        int   ij = __shfl(idx, j, 64);
        const float4* vr = (const float4*)(V + (size_t)ij * 512);
        float4 v0 = vr[lane * 2], v1 = vr[lane * 2 + 1];
        acc0.x += wj * v0.x; acc0.y += wj * v0.y; acc0.z += wj * v0.z; acc0.w += wj * v0.w;
        acc1.x += wj * v1.x; acc1.y += wj * v1.y; acc1.z += wj * v1.z; acc1.w += wj * v1.w;
    }
    float gr = g_out[row];
    float4 o0 = {gr * acc0.x, gr * acc0.y, gr * acc0.z, gr * acc0.w};
    float4 o1 = {gr * acc1.x, gr * acc1.y, gr * acc1.z, gr * acc1.w};
    float4* yp = (float4*)(y + (size_t)row * 512);
    yp[lane * 2]     = o0;
    yp[lane * 2 + 1] = o1;
}

extern "C" void kernel_launch(void* const* d_in, const int* in_sizes, int n_in,
                              void* d_out, int out_size, void* d_ws, size_t ws_size,
                              hipStream_t stream) {
    const float* x = (const float*)d_in[0];
    const float* K = (const float*)d_in[1];
    const float* V = (const float*)d_in[2];
    const float* s = (const float*)d_in[3];

    float* y     = (float*)d_out;                       // [32768][512]
    float* f_out = y + (size_t)NB * 512;                // [32768]
    float* g_out = f_out + NB;                          // [32768]
    float* attn  = g_out + NB;                          // [32768][2048]

    char* ws = (char*)d_ws;
    u16*    xn     = (u16*)ws;                          // 33,554,432 B
    u16*    kn     = (u16*)(ws + 33554432);             //  2,097,152 B -> 35,651,584
    float*  logs   = (float*)(ws + 35651584);           //      8,192 B -> 35,659,776
    float*  counts = (float*)(ws + 35659776);           //      8,192 B -> 35,667,968
    double* invKn  = (double*)(ws + 35667968);          //     16,384 B -> 35,684,352
    float*  top8v  = (float*)(ws + 35684352);           //  1,048,576 B -> 36,732,928
    u16*    top8i  = (u16*)(ws + 36732928);             //    524,288 B -> 37,257,216
    u16*    S2     = (u16*)(ws + 67108864);             // 134,217,728 B bf16 scores

    rownorm_kernel<<<NB / 4, 256, 0, stream>>>(x, xn);
    kprep_kernel<<<NM / 4, 256, 0, stream>>>(K, kn, invKn, s, logs, counts);
    gemm_kernel<<<1024, 512, 0, stream>>>(xn, kn, S2);
    candrefine_kernel<<<NB / 4, 256, 0, stream>>>(S2, x, K, invKn,
                                                  top8v, top8i, f_out, g_out, counts);
    finalize_kernel<<<NB / 4, 256, 0, stream>>>(top8v, top8i, counts, logs, V,
                                                g_out, y, attn);
}